// Round 1
// baseline (1063.268 us; speedup 1.0000x reference)
//
#include <hip/hip_runtime.h>
#include <cstdint>
#include <cmath>

// ---------------------------------------------------------------------------
// Vit_Channel_Map: bn=16, C=64, P=16384, DIM=1024, HEADS=8, DH=128
//   xe  = x @ We^T + be + pos          [1024,1024]   (K=16384)  bf16 MFMA
//   q   = xe @ Wq_mean^T  (mean folded into Wq)  -> k = sigmoid(q @ Wk^T)
//   t   = (xe @ Wv^T) * k[b, d>>7, c]  [1024,1024]   (K=1024)   bf16 MFMA
//   out = t @ Wo^T + bo                [1024,16384]  (K=1024)   bf16 MFMA
// ---------------------------------------------------------------------------

typedef __attribute__((ext_vector_type(8))) short short8;
typedef __attribute__((ext_vector_type(4))) float f32x4;

#define DIMD 1024
#define NCH  64
#define NHEAD 8
#define DHEAD 128

// fp32 -> bf16 bits, round-to-nearest-even (inputs are finite, no NaN path)
__device__ inline unsigned short f2bf(float f) {
  union { float f; unsigned u; } a; a.f = f;
  unsigned u = a.u;
  unsigned r = (u + 0x7fffu + ((u >> 16) & 1u)) >> 16;
  return (unsigned short)r;
}
__device__ inline float bf2f(unsigned short h) {
  union { unsigned u; float f; } a; a.u = ((unsigned)h) << 16; return a.f;
}

// ---- Wq_mean: wqm[h][d] = (1/128) * sum_e Wq[h*128+e][d] ----
__global__ void wqm_kernel(const float* __restrict__ Wq, float* __restrict__ wqm) {
  int h = blockIdx.x;
  for (int d = threadIdx.x; d < DIMD; d += 256) {
    float s = 0.f;
    const float* p = Wq + (size_t)h * DHEAD * DIMD + d;
    #pragma unroll 4
    for (int e = 0; e < DHEAD; ++e) s += p[(size_t)e * DIMD];
    wqm[h * DIMD + d] = s * (1.0f / DHEAD);
  }
}

// ---- q = xe @ wqm^T ; k = sigmoid(q @ Wk^T), one block per batch ----
__global__ void qk_kernel(const unsigned short* __restrict__ xe,
                          const float* __restrict__ wqm,
                          const float* __restrict__ Wk,
                          float* __restrict__ kout) {
  int b = blockIdx.x;
  __shared__ float qs[NHEAD][NCH];
  for (int t = threadIdx.x; t < NHEAD * NCH; t += 256) {
    int h = t >> 6, c = t & 63;
    const unsigned short* xr = xe + (size_t)(b * NCH + c) * DIMD;
    const float* wr = wqm + h * DIMD;
    float s = 0.f;
    #pragma unroll 8
    for (int d = 0; d < DIMD; ++d) s += bf2f(xr[d]) * wr[d];
    qs[h][c] = s;
  }
  __syncthreads();
  for (int t = threadIdx.x; t < NHEAD * NCH; t += 256) {
    int h = t >> 6, f = t & 63;
    float s = 0.f;
    #pragma unroll
    for (int c = 0; c < NCH; ++c) s += qs[h][c] * Wk[f * NCH + c];
    kout[b * (NHEAD * NCH) + h * NCH + f] = 1.f / (1.f + expf(-s));
  }
}

// ---- generic C = A @ B^T GEMM, bf16 MFMA, fused epilogues ----
// A: [M][K] (fp32 or bf16-bits), B: [N][K] fp32. BK=32.
// MODE 0: C_bf16 = acc + be[col] + pos[row&63][col]
// MODE 1: C_bf16 = acc * ksc[row>>6][col>>7][row&63]
// MODE 2: C_f32  = acc + bo[col]
template<int MODE, bool ABF16, int BM, int BN>
__global__ __launch_bounds__(256) void gemm_bt(
    const void* __restrict__ Ap, const float* __restrict__ B,
    void* __restrict__ C, const float* __restrict__ bias,
    const float* __restrict__ posp, const float* __restrict__ ksc,
    int M, int N, int K)
{
  constexpr int BK = 32;
  constexpr int LDR = BK + 8;            // +8 bf16 pad: b128 reads stay <=2-way
  __shared__ __align__(16) unsigned short As[BM][LDR];
  __shared__ __align__(16) unsigned short Bs[BN][LDR];

  const int tid = threadIdx.x;
  const int m0 = blockIdx.y * BM;
  const int n0 = blockIdx.x * BN;

  constexpr int EA = BM * BK / 256;      // elements staged per thread (8 or 16)
  constexpr int EB = BN * BK / 256;
  constexpr int MI = BM / 32;            // 16x16 tiles per wave (rows)
  constexpr int NI = BN / 32;

  const int lane = tid & 63, wave = tid >> 6;
  const int wr = (wave >> 1) * (BM / 2);
  const int wc = (wave & 1) * (BN / 2);
  const int q = lane >> 4, rl = lane & 15;

  f32x4 acc[MI][NI] = {};

  for (int k0 = 0; k0 < K; k0 += BK) {
    // ---- stage A tile ----
    {
      constexpr int CPR = BK / EA;
      int row = tid / CPR;
      int cs  = (tid % CPR) * EA;
      if (ABF16) {
        const unsigned short* a = (const unsigned short*)Ap + (size_t)(m0 + row) * K + k0 + cs;
        #pragma unroll
        for (int v = 0; v < EA / 8; ++v)
          *(uint4*)&As[row][cs + v * 8] = *(const uint4*)(a + v * 8);
      } else {
        const float* a = (const float*)Ap + (size_t)(m0 + row) * K + k0 + cs;
        #pragma unroll
        for (int v = 0; v < EA / 8; ++v) {
          float4 f0 = *(const float4*)(a + v * 8);
          float4 f1 = *(const float4*)(a + v * 8 + 4);
          uint4 u;
          u.x = (unsigned)f2bf(f0.x) | ((unsigned)f2bf(f0.y) << 16);
          u.y = (unsigned)f2bf(f0.z) | ((unsigned)f2bf(f0.w) << 16);
          u.z = (unsigned)f2bf(f1.x) | ((unsigned)f2bf(f1.y) << 16);
          u.w = (unsigned)f2bf(f1.z) | ((unsigned)f2bf(f1.w) << 16);
          *(uint4*)&As[row][cs + v * 8] = u;
        }
      }
    }
    // ---- stage B tile (always fp32 weights) ----
    {
      constexpr int CPR = BK / EB;
      int row = tid / CPR;
      int cs  = (tid % CPR) * EB;
      const float* b = B + (size_t)(n0 + row) * K + k0 + cs;
      #pragma unroll
      for (int v = 0; v < EB / 8; ++v) {
        float4 f0 = *(const float4*)(b + v * 8);
        float4 f1 = *(const float4*)(b + v * 8 + 4);
        uint4 u;
        u.x = (unsigned)f2bf(f0.x) | ((unsigned)f2bf(f0.y) << 16);
        u.y = (unsigned)f2bf(f0.z) | ((unsigned)f2bf(f0.w) << 16);
        u.z = (unsigned)f2bf(f1.x) | ((unsigned)f2bf(f1.y) << 16);
        u.w = (unsigned)f2bf(f1.z) | ((unsigned)f2bf(f1.w) << 16);
        *(uint4*)&Bs[row][cs + v * 8] = u;
      }
    }
    __syncthreads();

    // ---- MFMA: A[m=rl][k=q*8+j], B[n=rl][k=q*8+j], D[row=q*4+r][col=rl] ----
    short8 af[MI], bf[NI];
    #pragma unroll
    for (int i = 0; i < MI; ++i)
      af[i] = *(const short8*)&As[wr + i * 16 + rl][q * 8];
    #pragma unroll
    for (int j = 0; j < NI; ++j)
      bf[j] = *(const short8*)&Bs[wc + j * 16 + rl][q * 8];
    #pragma unroll
    for (int i = 0; i < MI; ++i)
      #pragma unroll
      for (int j = 0; j < NI; ++j)
        acc[i][j] = __builtin_amdgcn_mfma_f32_16x16x32_bf16(af[i], bf[j], acc[i][j], 0, 0, 0);

    __syncthreads();
  }

  // ---- epilogue ----
  #pragma unroll
  for (int i = 0; i < MI; ++i) {
    #pragma unroll
    for (int j = 0; j < NI; ++j) {
      #pragma unroll
      for (int r = 0; r < 4; ++r) {
        int row = m0 + wr + i * 16 + q * 4 + r;
        int col = n0 + wc + j * 16 + rl;
        float v = acc[i][j][r];
        if (MODE == 0) {
          v += bias[col] + posp[(size_t)(row & 63) * DIMD + col];
          ((unsigned short*)C)[(size_t)row * N + col] = f2bf(v);
        } else if (MODE == 1) {
          v *= ksc[((row >> 6) * NHEAD + (col >> 7)) * NCH + (row & 63)];
          ((unsigned short*)C)[(size_t)row * N + col] = f2bf(v);
        } else {
          ((float*)C)[(size_t)row * N + col] = v + bias[col];
        }
      }
    }
  }
}

extern "C" void kernel_launch(void* const* d_in, const int* in_sizes, int n_in,
                              void* d_out, int out_size, void* d_ws, size_t ws_size,
                              hipStream_t stream) {
  const float* x   = (const float*)d_in[0];   // [1024][16384]
  const float* We  = (const float*)d_in[1];   // [1024][16384]
  const float* be  = (const float*)d_in[2];   // [1024]
  const float* pos = (const float*)d_in[3];   // [64][1024]
  const float* Wq  = (const float*)d_in[4];   // [1024][1024]
  const float* Wk  = (const float*)d_in[5];   // [64][64]
  const float* Wv  = (const float*)d_in[6];   // [1024][1024]
  const float* Wo  = (const float*)d_in[7];   // [16384][1024]
  const float* bo  = (const float*)d_in[8];   // [16384]
  float* out = (float*)d_out;                 // [1024][16384] fp32

  char* ws = (char*)d_ws;
  unsigned short* xe = (unsigned short*)ws;                    // 2 MB bf16 [1024][1024]
  unsigned short* t  = (unsigned short*)(ws + (2u << 20));     // 2 MB bf16 [1024][1024]
  float* wqm = (float*)(ws + (4u << 20));                      // 32 KB [8][1024]
  float* kv  = (float*)(ws + (4u << 20) + (32u << 10));        // 32 KB [16][8][64]

  wqm_kernel<<<dim3(NHEAD), 256, 0, stream>>>(Wq, wqm);

  // xe = x @ We^T + be + pos   (M=1024, N=1024, K=16384), 256 blocks
  gemm_bt<0, false, 64, 64><<<dim3(16, 16), 256, 0, stream>>>(
      x, We, xe, be, pos, nullptr, 1024, 1024, 16384);

  qk_kernel<<<dim3(16), 256, 0, stream>>>(xe, wqm, Wk, kv);

  // t = (xe @ Wv^T) * k   (M=1024, N=1024, K=1024), 256 blocks
  gemm_bt<1, true, 64, 64><<<dim3(16, 16), 256, 0, stream>>>(
      xe, Wv, t, nullptr, nullptr, kv, 1024, 1024, 1024);

  // out = t @ Wo^T + bo   (M=1024, N=16384, K=1024), 1024 blocks
  gemm_bt<2, true, 128, 128><<<dim3(128, 8), 256, 0, stream>>>(
      t, Wo, out, bo, nullptr, nullptr, 1024, 16384, 1024);
}

// Round 2
// 497.974 us; speedup vs baseline: 2.1352x; 2.1352x over previous
//
#include <hip/hip_runtime.h>
#include <cstdint>
#include <cmath>

// ---------------------------------------------------------------------------
// Vit_Channel_Map: bn=16, C=64, P=16384, DIM=1024, HEADS=8, DH=128
// Fast path (needs ~73.5MB ws):
//   cvt x,We,Wv,Wo -> bf16;  GEMM1 (splitK=8, partials in d_out) -> reduce(+be+pos)
//   -> xe ; qk ; GEMM-v (splitK=4) -> reduce(*k) -> t ; final GEMM (+bo) -> d_out.
// GEMMs: m97 structure — 128x128 tile, BK=32, global_load_lds width 16,
// unpadded [128][32] bf16 LDS, 16x16x32 bf16 MFMA, 4 waves x 4x4 acc.
// Fallback path (ws < 73.5MB): round-1 kernels (proven correct).
// ---------------------------------------------------------------------------

typedef __attribute__((ext_vector_type(8))) short short8;
typedef __attribute__((ext_vector_type(4))) float f32x4;

#define DIMD 1024
#define NCH  64
#define NHEAD 8
#define DHEAD 128

typedef __attribute__((address_space(1))) unsigned int gu32;
typedef __attribute__((address_space(3))) unsigned int lu32;

__device__ __forceinline__ void gload_lds16(const void* g, void* l) {
  __builtin_amdgcn_global_load_lds((gu32*)g, (lu32*)l, 16, 0, 0);
}

// fp32 -> bf16 bits, round-to-nearest-even
__device__ __forceinline__ unsigned short f2bf(float f) {
  union { float f; unsigned u; } a; a.f = f;
  unsigned u = a.u;
  unsigned r = (u + 0x7fffu + ((u >> 16) & 1u)) >> 16;
  return (unsigned short)r;
}
__device__ __forceinline__ float bf2f(unsigned short h) {
  union { unsigned u; float f; } a; a.u = ((unsigned)h) << 16; return a.f;
}

// ---- elementwise fp32 -> bf16, 8 elems/thread ----
__global__ __launch_bounds__(256) void cvt_bf16_kernel(
    const float* __restrict__ in, unsigned short* __restrict__ out, int n8) {
  int i = blockIdx.x * 256 + threadIdx.x;
  if (i >= n8) return;
  const float4* p = (const float4*)in + (size_t)i * 2;
  float4 f0 = p[0], f1 = p[1];
  uint4 u;
  u.x = (unsigned)f2bf(f0.x) | ((unsigned)f2bf(f0.y) << 16);
  u.y = (unsigned)f2bf(f0.z) | ((unsigned)f2bf(f0.w) << 16);
  u.z = (unsigned)f2bf(f1.x) | ((unsigned)f2bf(f1.y) << 16);
  u.w = (unsigned)f2bf(f1.z) | ((unsigned)f2bf(f1.w) << 16);
  ((uint4*)out)[i] = u;
}

// ---- Wq_mean: wqm[h][d] = (1/128) * sum_e Wq[h*128+e][d] ----
__global__ void wqm_kernel(const float* __restrict__ Wq, float* __restrict__ wqm) {
  int h = blockIdx.x;
  for (int d = threadIdx.x; d < DIMD; d += 256) {
    float s = 0.f;
    const float* p = Wq + (size_t)h * DHEAD * DIMD + d;
    #pragma unroll 4
    for (int e = 0; e < DHEAD; ++e) s += p[(size_t)e * DIMD];
    wqm[h * DIMD + d] = s * (1.0f / DHEAD);
  }
}

// ---- q = xe @ wqm^T ; k = sigmoid(q @ Wk^T), one block per batch ----
__global__ void qk_kernel(const unsigned short* __restrict__ xe,
                          const float* __restrict__ wqm,
                          const float* __restrict__ Wk,
                          float* __restrict__ kout) {
  int b = blockIdx.x;
  __shared__ float qs[NHEAD][NCH];
  for (int t = threadIdx.x; t < NHEAD * NCH; t += 256) {
    int h = t >> 6, c = t & 63;
    const uint4* xr = (const uint4*)(xe + (size_t)(b * NCH + c) * DIMD);
    const float* wr = wqm + h * DIMD;
    float s = 0.f;
    #pragma unroll 4
    for (int d8 = 0; d8 < DIMD / 8; ++d8) {
      uint4 v = xr[d8];
      s += bf2f((unsigned short)(v.x & 0xffff)) * wr[d8 * 8 + 0];
      s += bf2f((unsigned short)(v.x >> 16))    * wr[d8 * 8 + 1];
      s += bf2f((unsigned short)(v.y & 0xffff)) * wr[d8 * 8 + 2];
      s += bf2f((unsigned short)(v.y >> 16))    * wr[d8 * 8 + 3];
      s += bf2f((unsigned short)(v.z & 0xffff)) * wr[d8 * 8 + 4];
      s += bf2f((unsigned short)(v.z >> 16))    * wr[d8 * 8 + 5];
      s += bf2f((unsigned short)(v.w & 0xffff)) * wr[d8 * 8 + 6];
      s += bf2f((unsigned short)(v.w >> 16))    * wr[d8 * 8 + 7];
    }
    qs[h][c] = s;
  }
  __syncthreads();
  for (int t = threadIdx.x; t < NHEAD * NCH; t += 256) {
    int h = t >> 6, f = t & 63;
    float s = 0.f;
    #pragma unroll
    for (int c = 0; c < NCH; ++c) s += qs[h][c] * Wk[f * NCH + c];
    kout[b * (NHEAD * NCH) + h * NCH + f] = 1.f / (1.f + expf(-s));
  }
}

// ---- m97-style bf16 GEMM: C = A @ B^T. A:[M][K] bf16, B:[N][K] bf16 ----
// MODE 3: raw fp32 partial store to C[z][M][N]  (split-K)
// MODE 2: C_f32 = acc + bias[col]               (final)
template<int MODE>
__global__ __launch_bounds__(256) void gemm_bf16(
    const unsigned short* __restrict__ A, const unsigned short* __restrict__ B,
    float* __restrict__ C, const float* __restrict__ bias,
    int M, int N, int K, int Ksub)
{
  __shared__ __align__(16) unsigned short As[128][32];
  __shared__ __align__(16) unsigned short Bs[128][32];

  const int tid  = threadIdx.x;
  const int lane = tid & 63, wave = tid >> 6;
  const int m0 = blockIdx.y * 128, n0 = blockIdx.x * 128;
  const int kbeg = blockIdx.z * Ksub;
  const int lrow = lane >> 2;         // 0..15
  const int lcol = (lane & 3) * 8;    // 0,8,16,24
  const int q = lane >> 4, rl = lane & 15;
  const int wr = (wave >> 1) * 64, wc = (wave & 1) * 64;

  const unsigned short* ga = A + (size_t)(m0 + wave * 32 + lrow) * K + kbeg + lcol;
  const unsigned short* gb = B + (size_t)(n0 + wave * 32 + lrow) * K + kbeg + lcol;
  unsigned short* la0 = &As[wave * 32][0];
  unsigned short* la1 = &As[wave * 32 + 16][0];
  unsigned short* lb0 = &Bs[wave * 32][0];
  unsigned short* lb1 = &Bs[wave * 32 + 16][0];

  f32x4 acc[4][4] = {};

  for (int k0 = 0; k0 < Ksub; k0 += 32) {
    gload_lds16(ga,                      la0);
    gload_lds16(ga + (size_t)16 * K,     la1);
    gload_lds16(gb,                      lb0);
    gload_lds16(gb + (size_t)16 * K,     lb1);
    ga += 32; gb += 32;
    __syncthreads();

    short8 af[4], bf[4];
    #pragma unroll
    for (int i = 0; i < 4; ++i)
      af[i] = *(const short8*)&As[wr + i * 16 + rl][q * 8];
    #pragma unroll
    for (int j = 0; j < 4; ++j)
      bf[j] = *(const short8*)&Bs[wc + j * 16 + rl][q * 8];
    #pragma unroll
    for (int i = 0; i < 4; ++i)
      #pragma unroll
      for (int j = 0; j < 4; ++j)
        acc[i][j] = __builtin_amdgcn_mfma_f32_16x16x32_bf16(af[i], bf[j], acc[i][j], 0, 0, 0);

    __syncthreads();
  }

  const size_t zoff = (MODE == 3) ? (size_t)blockIdx.z * (size_t)M * (size_t)N : 0;
  #pragma unroll
  for (int i = 0; i < 4; ++i) {
    #pragma unroll
    for (int j = 0; j < 4; ++j) {
      #pragma unroll
      for (int r = 0; r < 4; ++r) {
        int row = m0 + wr + i * 16 + q * 4 + r;
        int col = n0 + wc + j * 16 + rl;
        if (MODE == 3) {
          C[zoff + (size_t)row * N + col] = acc[i][j][r];
        } else {
          C[(size_t)row * N + col] = acc[i][j][r] + bias[col];
        }
      }
    }
  }
}

// ---- reduce splitK=8 partials + be + pos -> bf16 xe ----
__global__ __launch_bounds__(256) void reduce1_kernel(
    const float* __restrict__ part, const float* __restrict__ be,
    const float* __restrict__ pos, unsigned short* __restrict__ xe) {
  int i = blockIdx.x * 256 + threadIdx.x;       // 0 .. 1024*1024/4
  size_t base = (size_t)i * 4;
  int row = i >> 8, col = (i & 255) * 4;
  float4 s = {0.f, 0.f, 0.f, 0.f};
  #pragma unroll
  for (int sk = 0; sk < 8; ++sk) {
    float4 p = *(const float4*)(part + (size_t)sk * (DIMD * DIMD) + base);
    s.x += p.x; s.y += p.y; s.z += p.z; s.w += p.w;
  }
  float4 bv = *(const float4*)(be + col);
  float4 pv = *(const float4*)(pos + (size_t)(row & 63) * DIMD + col);
  uint2 u;
  u.x = (unsigned)f2bf(s.x + bv.x + pv.x) | ((unsigned)f2bf(s.y + bv.y + pv.y) << 16);
  u.y = (unsigned)f2bf(s.z + bv.z + pv.z) | ((unsigned)f2bf(s.w + bv.w + pv.w) << 16);
  *(uint2*)(xe + base) = u;
}

// ---- reduce splitK=4 partials * k-scale -> bf16 t ----
__global__ __launch_bounds__(256) void reduce2_kernel(
    const float* __restrict__ part, const float* __restrict__ kv,
    unsigned short* __restrict__ t) {
  int i = blockIdx.x * 256 + threadIdx.x;
  size_t base = (size_t)i * 4;
  int row = i >> 8, col = (i & 255) * 4;
  float4 s = {0.f, 0.f, 0.f, 0.f};
  #pragma unroll
  for (int sk = 0; sk < 4; ++sk) {
    float4 p = *(const float4*)(part + (size_t)sk * (DIMD * DIMD) + base);
    s.x += p.x; s.y += p.y; s.z += p.z; s.w += p.w;
  }
  float sc = kv[((row >> 6) * NHEAD + (col >> 7)) * NCH + (row & 63)];
  uint2 u;
  u.x = (unsigned)f2bf(s.x * sc) | ((unsigned)f2bf(s.y * sc) << 16);
  u.y = (unsigned)f2bf(s.z * sc) | ((unsigned)f2bf(s.w * sc) << 16);
  *(uint2*)(t + base) = u;
}

// ===========================================================================
// Fallback (round-1, proven): fp32-staged MFMA GEMM with fused cvt
// ===========================================================================
template<int MODE, bool ABF16, int BM, int BN>
__global__ __launch_bounds__(256) void gemm_bt(
    const void* __restrict__ Ap, const float* __restrict__ B,
    void* __restrict__ C, const float* __restrict__ bias,
    const float* __restrict__ posp, const float* __restrict__ ksc,
    int M, int N, int K)
{
  constexpr int BK = 32;
  constexpr int LDR = BK + 8;
  __shared__ __align__(16) unsigned short As[BM][LDR];
  __shared__ __align__(16) unsigned short Bs[BN][LDR];

  const int tid = threadIdx.x;
  const int m0 = blockIdx.y * BM;
  const int n0 = blockIdx.x * BN;
  constexpr int EA = BM * BK / 256;
  constexpr int EB = BN * BK / 256;
  constexpr int MI = BM / 32;
  constexpr int NI = BN / 32;
  const int lane = tid & 63, wave = tid >> 6;
  const int wr = (wave >> 1) * (BM / 2);
  const int wc = (wave & 1) * (BN / 2);
  const int q = lane >> 4, rl = lane & 15;

  f32x4 acc[MI][NI] = {};

  for (int k0 = 0; k0 < K; k0 += BK) {
    {
      constexpr int CPR = BK / EA;
      int row = tid / CPR;
      int cs  = (tid % CPR) * EA;
      if (ABF16) {
        const unsigned short* a = (const unsigned short*)Ap + (size_t)(m0 + row) * K + k0 + cs;
        #pragma unroll
        for (int v = 0; v < EA / 8; ++v)
          *(uint4*)&As[row][cs + v * 8] = *(const uint4*)(a + v * 8);
      } else {
        const float* a = (const float*)Ap + (size_t)(m0 + row) * K + k0 + cs;
        #pragma unroll
        for (int v = 0; v < EA / 8; ++v) {
          float4 f0 = *(const float4*)(a + v * 8);
          float4 f1 = *(const float4*)(a + v * 8 + 4);
          uint4 u;
          u.x = (unsigned)f2bf(f0.x) | ((unsigned)f2bf(f0.y) << 16);
          u.y = (unsigned)f2bf(f0.z) | ((unsigned)f2bf(f0.w) << 16);
          u.z = (unsigned)f2bf(f1.x) | ((unsigned)f2bf(f1.y) << 16);
          u.w = (unsigned)f2bf(f1.z) | ((unsigned)f2bf(f1.w) << 16);
          *(uint4*)&As[row][cs + v * 8] = u;
        }
      }
    }
    {
      constexpr int CPR = BK / EB;
      int row = tid / CPR;
      int cs  = (tid % CPR) * EB;
      const float* b = B + (size_t)(n0 + row) * K + k0 + cs;
      #pragma unroll
      for (int v = 0; v < EB / 8; ++v) {
        float4 f0 = *(const float4*)(b + v * 8);
        float4 f1 = *(const float4*)(b + v * 8 + 4);
        uint4 u;
        u.x = (unsigned)f2bf(f0.x) | ((unsigned)f2bf(f0.y) << 16);
        u.y = (unsigned)f2bf(f0.z) | ((unsigned)f2bf(f0.w) << 16);
        u.z = (unsigned)f2bf(f1.x) | ((unsigned)f2bf(f1.y) << 16);
        u.w = (unsigned)f2bf(f1.z) | ((unsigned)f2bf(f1.w) << 16);
        *(uint4*)&Bs[row][cs + v * 8] = u;
      }
    }
    __syncthreads();

    short8 af[MI], bf[NI];
    #pragma unroll
    for (int i = 0; i < MI; ++i)
      af[i] = *(const short8*)&As[wr + i * 16 + rl][q * 8];
    #pragma unroll
    for (int j = 0; j < NI; ++j)
      bf[j] = *(const short8*)&Bs[wc + j * 16 + rl][q * 8];
    #pragma unroll
    for (int i = 0; i < MI; ++i)
      #pragma unroll
      for (int j = 0; j < NI; ++j)
        acc[i][j] = __builtin_amdgcn_mfma_f32_16x16x32_bf16(af[i], bf[j], acc[i][j], 0, 0, 0);

    __syncthreads();
  }

  #pragma unroll
  for (int i = 0; i < MI; ++i) {
    #pragma unroll
    for (int j = 0; j < NI; ++j) {
      #pragma unroll
      for (int r = 0; r < 4; ++r) {
        int row = m0 + wr + i * 16 + q * 4 + r;
        int col = n0 + wc + j * 16 + rl;
        float v = acc[i][j][r];
        if (MODE == 0) {
          v += bias[col] + posp[(size_t)(row & 63) * DIMD + col];
          ((unsigned short*)C)[(size_t)row * N + col] = f2bf(v);
        } else if (MODE == 1) {
          v *= ksc[((row >> 6) * NHEAD + (col >> 7)) * NCH + (row & 63)];
          ((unsigned short*)C)[(size_t)row * N + col] = f2bf(v);
        } else {
          ((float*)C)[(size_t)row * N + col] = v + bias[col];
        }
      }
    }
  }
}

extern "C" void kernel_launch(void* const* d_in, const int* in_sizes, int n_in,
                              void* d_out, int out_size, void* d_ws, size_t ws_size,
                              hipStream_t stream) {
  const float* x   = (const float*)d_in[0];   // [1024][16384]
  const float* We  = (const float*)d_in[1];   // [1024][16384]
  const float* be  = (const float*)d_in[2];   // [1024]
  const float* pos = (const float*)d_in[3];   // [64][1024]
  const float* Wq  = (const float*)d_in[4];   // [1024][1024]
  const float* Wk  = (const float*)d_in[5];   // [64][64]
  const float* Wv  = (const float*)d_in[6];   // [1024][1024]
  const float* Wo  = (const float*)d_in[7];   // [16384][1024]
  const float* bo  = (const float*)d_in[8];   // [16384]
  float* out = (float*)d_out;                 // [1024][16384] fp32

  const size_t MB = 1u << 20;
  const size_t FAST_WS = 70 * MB + 64 * 1024;   // 73,465,856 B

  if (ws_size >= FAST_WS) {
    char* ws = (char*)d_ws;
    unsigned short* We_bf = (unsigned short*)(ws + 0);          // 32 MB
    unsigned short* Wo_bf = (unsigned short*)(ws + 32 * MB);    // 32 MB
    unsigned short* Wv_bf = (unsigned short*)(ws + 64 * MB);    // 2 MB
    unsigned short* xe    = (unsigned short*)(ws + 66 * MB);    // 2 MB
    unsigned short* t     = (unsigned short*)(ws + 68 * MB);    // 2 MB
    float* wqm = (float*)(ws + 70 * MB);                        // 32 KB
    float* kv  = (float*)(ws + 70 * MB + 32 * 1024);            // 32 KB

    char* ob = (char*)d_out;
    unsigned short* x_bf  = (unsigned short*)(ob + 0);          // 32 MB (dead after GEMM1)
    float* part1 = (float*)(ob + 32 * MB);                      // [8][1024][1024] 32 MB
    float* part2 = (float*)(ob + 0);                            // [4][1024][1024] 16 MB

    // conversions
    cvt_bf16_kernel<<<dim3(8192), 256, 0, stream>>>(x,  x_bf,  16777216 / 8);
    cvt_bf16_kernel<<<dim3(8192), 256, 0, stream>>>(We, We_bf, 16777216 / 8);
    cvt_bf16_kernel<<<dim3(512),  256, 0, stream>>>(Wv, Wv_bf, 1048576 / 8);
    cvt_bf16_kernel<<<dim3(8192), 256, 0, stream>>>(Wo, Wo_bf, 16777216 / 8);
    wqm_kernel<<<dim3(NHEAD), 256, 0, stream>>>(Wq, wqm);

    // GEMM1: x @ We^T, splitK=8 -> part1
    gemm_bf16<3><<<dim3(8, 8, 8), 256, 0, stream>>>(
        x_bf, We_bf, part1, nullptr, 1024, 1024, 16384, 2048);
    reduce1_kernel<<<dim3(1024), 256, 0, stream>>>(part1, be, pos, xe);

    qk_kernel<<<dim3(16), 256, 0, stream>>>(xe, wqm, Wk, kv);

    // GEMM-v: xe @ Wv^T, splitK=4 -> part2 (x_bf is dead now)
    gemm_bf16<3><<<dim3(8, 8, 4), 256, 0, stream>>>(
        xe, Wv_bf, part2, nullptr, 1024, 1024, 1024, 256);
    reduce2_kernel<<<dim3(1024), 256, 0, stream>>>(part2, kv, t);

    // final: t @ Wo^T + bo -> out (overwrites everything in d_out)
    gemm_bf16<2><<<dim3(128, 8, 1), 256, 0, stream>>>(
        t, Wo_bf, out, bo, 1024, 16384, 1024, 1024);
  } else {
    // fallback: round-1 path (needs ~4.1 MB ws)
    char* ws = (char*)d_ws;
    unsigned short* xe = (unsigned short*)ws;
    unsigned short* t  = (unsigned short*)(ws + (2u << 20));
    float* wqm = (float*)(ws + (4u << 20));
    float* kv  = (float*)(ws + (4u << 20) + (32u << 10));

    wqm_kernel<<<dim3(NHEAD), 256, 0, stream>>>(Wq, wqm);
    gemm_bt<0, false, 64, 64><<<dim3(16, 16), 256, 0, stream>>>(
        x, We, xe, be, pos, nullptr, 1024, 1024, 16384);
    qk_kernel<<<dim3(16), 256, 0, stream>>>(xe, wqm, Wk, kv);
    gemm_bt<1, true, 64, 64><<<dim3(16, 16), 256, 0, stream>>>(
        xe, Wv, t, nullptr, nullptr, kv, 1024, 1024, 1024);
    gemm_bt<2, true, 128, 128><<<dim3(128, 8), 256, 0, stream>>>(
        t, Wo, out, bo, nullptr, nullptr, 1024, 16384, 1024);
  }
}

// Round 3
// 393.251 us; speedup vs baseline: 2.7038x; 1.2663x over previous
//
#include <hip/hip_runtime.h>
#include <cstdint>
#include <cmath>

// ---------------------------------------------------------------------------
// Vit_Channel_Map: bn=16, C=64, P=16384, DIM=1024, HEADS=8, DH=128
// Tier A (ws >= ~102MB): cvt weights+x -> bf16 (x_bf in ws);
//   GEMM1 splitK=16 (partials = all 64MB of d_out), XCD-pinned K-slices;
//   reduce(+be+pos) -> xe ; wqm/qk (parallelized) ; GEMM-v splitK=8 ;
//   reduce(*k) -> t ; final GEMM XCD-pinned Wo chunks (+bo) -> d_out.
// Tier B (ws >= ~73.5MB): round-2 layout (x_bf in d_out, splitK=8) + XCD decode.
// Tier C: round-1 fused-cvt GEMMs (proven, ~4MB ws).
// GEMM core: m97 structure — 128x128 tile, BK=32, global_load_lds width 16,
// unpadded [128][32] bf16 LDS, 16x16x32 bf16 MFMA, 4 waves x 4x4 acc.
// ---------------------------------------------------------------------------

typedef __attribute__((ext_vector_type(8))) short short8;
typedef __attribute__((ext_vector_type(4))) float f32x4;

#define DIMD 1024
#define NCH  64
#define NHEAD 8
#define DHEAD 128

typedef __attribute__((address_space(1))) unsigned int gu32;
typedef __attribute__((address_space(3))) unsigned int lu32;

__device__ __forceinline__ void gload_lds16(const void* g, void* l) {
  __builtin_amdgcn_global_load_lds((gu32*)g, (lu32*)l, 16, 0, 0);
}

__device__ __forceinline__ unsigned short f2bf(float f) {
  union { float f; unsigned u; } a; a.f = f;
  unsigned u = a.u;
  unsigned r = (u + 0x7fffu + ((u >> 16) & 1u)) >> 16;
  return (unsigned short)r;
}
__device__ __forceinline__ float bf2f(unsigned short h) {
  union { unsigned u; float f; } a; a.u = ((unsigned)h) << 16; return a.f;
}

// ---- elementwise fp32 -> bf16, 8 elems/thread ----
__global__ __launch_bounds__(256) void cvt_bf16_kernel(
    const float* __restrict__ in, unsigned short* __restrict__ out, int n8) {
  int i = blockIdx.x * 256 + threadIdx.x;
  if (i >= n8) return;
  const float4* p = (const float4*)in + (size_t)i * 2;
  float4 f0 = p[0], f1 = p[1];
  uint4 u;
  u.x = (unsigned)f2bf(f0.x) | ((unsigned)f2bf(f0.y) << 16);
  u.y = (unsigned)f2bf(f0.z) | ((unsigned)f2bf(f0.w) << 16);
  u.z = (unsigned)f2bf(f1.x) | ((unsigned)f2bf(f1.y) << 16);
  u.w = (unsigned)f2bf(f1.z) | ((unsigned)f2bf(f1.w) << 16);
  ((uint4*)out)[i] = u;
}

// ---- wqm[h][d] = mean_e Wq[h*128+e][d] ; 64 blocks (h, d-chunk of 128) ----
__global__ __launch_bounds__(256) void wqm2_kernel(
    const float* __restrict__ Wq, float* __restrict__ wqm) {
  int h = blockIdx.x >> 3, dbase = (blockIdx.x & 7) * 128;
  int d = threadIdx.x & 127, eh = threadIdx.x >> 7;   // eh in {0,1}
  const float* p = Wq + ((size_t)(h * DHEAD + eh * 64)) * DIMD + dbase + d;
  float s = 0.f;
  #pragma unroll 8
  for (int e = 0; e < 64; ++e) s += p[(size_t)e * DIMD];
  __shared__ float red[2][128];
  red[eh][d] = s;
  __syncthreads();
  if (eh == 0)
    wqm[h * DIMD + dbase + d] = (red[0][d] + red[1][d]) * (1.0f / DHEAD);
}

// ---- q = xe @ wqm^T ; k = sigmoid(q @ Wk^T). Grid (16 batch, 8 head) ----
__global__ __launch_bounds__(256) void qk2_kernel(
    const unsigned short* __restrict__ xe, const float* __restrict__ wqm,
    const float* __restrict__ Wk, float* __restrict__ kout) {
  int b = blockIdx.x, h = blockIdx.y;
  int c = threadIdx.x & 63, dq = threadIdx.x >> 6;    // dq: quarter of d
  __shared__ float red[64][4];
  __shared__ float qs[64];
  const uint4* xr = (const uint4*)(xe + ((size_t)(b * NCH + c)) * DIMD + dq * 256);
  const float* wr = wqm + h * DIMD + dq * 256;
  float s = 0.f;
  #pragma unroll 4
  for (int i = 0; i < 32; ++i) {
    uint4 v = xr[i];
    s += bf2f((unsigned short)(v.x & 0xffff)) * wr[i * 8 + 0];
    s += bf2f((unsigned short)(v.x >> 16))    * wr[i * 8 + 1];
    s += bf2f((unsigned short)(v.y & 0xffff)) * wr[i * 8 + 2];
    s += bf2f((unsigned short)(v.y >> 16))    * wr[i * 8 + 3];
    s += bf2f((unsigned short)(v.z & 0xffff)) * wr[i * 8 + 4];
    s += bf2f((unsigned short)(v.z >> 16))    * wr[i * 8 + 5];
    s += bf2f((unsigned short)(v.w & 0xffff)) * wr[i * 8 + 6];
    s += bf2f((unsigned short)(v.w >> 16))    * wr[i * 8 + 7];
  }
  red[c][dq] = s;
  __syncthreads();
  if (dq == 0) qs[c] = red[c][0] + red[c][1] + red[c][2] + red[c][3];
  __syncthreads();
  int f = c;
  float s2 = 0.f;
  #pragma unroll
  for (int i = 0; i < 16; ++i) {
    int cc = dq * 16 + i;
    s2 += qs[cc] * Wk[f * NCH + cc];
  }
  red[f][dq] = s2;
  __syncthreads();
  if (dq == 0) {
    float q = red[f][0] + red[f][1] + red[f][2] + red[f][3];
    kout[(b * NHEAD + h) * NCH + f] = 1.f / (1.f + expf(-q));
  }
}

// ---- m97-style bf16 GEMM: C = A @ B^T. A:[M][K] bf16, B:[N][K] bf16 ----
// MODE 3: fp32 partial store to C[z][M][N] (split-K) ; MODE 2: C_f32 = acc + bias
// LAYOUT (1D grid, XCD = bid&7 by round-robin dispatch):
//  0: splitK=8  : z=bid&7            ; r=bid>>3: n0=(r&7), m0=(r>>3)   [512 blk]
//  1: splitK=16 : z=(bid&7)|((bid>>3&1)<<3); r=bid>>4: n0=(r&7), m0=(r>>3) [1024]
//  2: no split  : nblk=(bid&7)+8*(bid>>6)  ; m0=(bid>>3)&7             [1024]
template<int MODE, int LAYOUT>
__global__ __launch_bounds__(256) void gemm_bf16(
    const unsigned short* __restrict__ A, const unsigned short* __restrict__ B,
    float* __restrict__ C, const float* __restrict__ bias,
    int M, int N, int K, int Ksub)
{
  __shared__ __align__(16) unsigned short As[128][32];
  __shared__ __align__(16) unsigned short Bs[128][32];

  const int bid = blockIdx.x;
  int m0, n0, kz;
  if (LAYOUT == 0) {
    kz = bid & 7; int r = bid >> 3; n0 = (r & 7) * 128; m0 = (r >> 3) * 128;
  } else if (LAYOUT == 1) {
    kz = (bid & 7) | (((bid >> 3) & 1) << 3);
    int r = bid >> 4; n0 = (r & 7) * 128; m0 = (r >> 3) * 128;
  } else {
    int nlo = bid & 7, nhi = bid >> 6;
    m0 = ((bid >> 3) & 7) * 128; n0 = (nlo + 8 * nhi) * 128; kz = 0;
  }

  const int tid  = threadIdx.x;
  const int lane = tid & 63, wave = tid >> 6;
  const int kbeg = kz * Ksub;
  const int lrow = lane >> 2;
  const int lcol = (lane & 3) * 8;
  const int q = lane >> 4, rl = lane & 15;
  const int wr = (wave >> 1) * 64, wc = (wave & 1) * 64;

  const unsigned short* ga = A + (size_t)(m0 + wave * 32 + lrow) * K + kbeg + lcol;
  const unsigned short* gb = B + (size_t)(n0 + wave * 32 + lrow) * K + kbeg + lcol;
  unsigned short* la0 = &As[wave * 32][0];
  unsigned short* la1 = &As[wave * 32 + 16][0];
  unsigned short* lb0 = &Bs[wave * 32][0];
  unsigned short* lb1 = &Bs[wave * 32 + 16][0];

  f32x4 acc[4][4] = {};

  for (int k0 = 0; k0 < Ksub; k0 += 32) {
    gload_lds16(ga,                  la0);
    gload_lds16(ga + (size_t)16 * K, la1);
    gload_lds16(gb,                  lb0);
    gload_lds16(gb + (size_t)16 * K, lb1);
    ga += 32; gb += 32;
    __syncthreads();

    short8 af[4], bf[4];
    #pragma unroll
    for (int i = 0; i < 4; ++i)
      af[i] = *(const short8*)&As[wr + i * 16 + rl][q * 8];
    #pragma unroll
    for (int j = 0; j < 4; ++j)
      bf[j] = *(const short8*)&Bs[wc + j * 16 + rl][q * 8];
    #pragma unroll
    for (int i = 0; i < 4; ++i)
      #pragma unroll
      for (int j = 0; j < 4; ++j)
        acc[i][j] = __builtin_amdgcn_mfma_f32_16x16x32_bf16(af[i], bf[j], acc[i][j], 0, 0, 0);

    __syncthreads();
  }

  const size_t zoff = (MODE == 3) ? (size_t)kz * (size_t)M * (size_t)N : 0;
  #pragma unroll
  for (int i = 0; i < 4; ++i) {
    #pragma unroll
    for (int j = 0; j < 4; ++j) {
      #pragma unroll
      for (int r = 0; r < 4; ++r) {
        int row = m0 + wr + i * 16 + q * 4 + r;
        int col = n0 + wc + j * 16 + rl;
        if (MODE == 3) {
          C[zoff + (size_t)row * N + col] = acc[i][j][r];
        } else {
          C[(size_t)row * N + col] = acc[i][j][r] + bias[col];
        }
      }
    }
  }
}

// ---- reduce NS splitK partials + be + pos -> bf16 xe ----
template<int NS>
__global__ __launch_bounds__(256) void reduce1_kernel(
    const float* __restrict__ part, const float* __restrict__ be,
    const float* __restrict__ pos, unsigned short* __restrict__ xe) {
  int i = blockIdx.x * 256 + threadIdx.x;
  size_t base = (size_t)i * 4;
  int row = i >> 8, col = (i & 255) * 4;
  float4 s = {0.f, 0.f, 0.f, 0.f};
  #pragma unroll
  for (int sk = 0; sk < NS; ++sk) {
    float4 p = *(const float4*)(part + (size_t)sk * (DIMD * DIMD) + base);
    s.x += p.x; s.y += p.y; s.z += p.z; s.w += p.w;
  }
  float4 bv = *(const float4*)(be + col);
  float4 pv = *(const float4*)(pos + (size_t)(row & 63) * DIMD + col);
  uint2 u;
  u.x = (unsigned)f2bf(s.x + bv.x + pv.x) | ((unsigned)f2bf(s.y + bv.y + pv.y) << 16);
  u.y = (unsigned)f2bf(s.z + bv.z + pv.z) | ((unsigned)f2bf(s.w + bv.w + pv.w) << 16);
  *(uint2*)(xe + base) = u;
}

// ---- reduce NS splitK partials * k-scale -> bf16 t ----
template<int NS>
__global__ __launch_bounds__(256) void reduce2_kernel(
    const float* __restrict__ part, const float* __restrict__ kv,
    unsigned short* __restrict__ t) {
  int i = blockIdx.x * 256 + threadIdx.x;
  size_t base = (size_t)i * 4;
  int row = i >> 8, col = (i & 255) * 4;
  float4 s = {0.f, 0.f, 0.f, 0.f};
  #pragma unroll
  for (int sk = 0; sk < NS; ++sk) {
    float4 p = *(const float4*)(part + (size_t)sk * (DIMD * DIMD) + base);
    s.x += p.x; s.y += p.y; s.z += p.z; s.w += p.w;
  }
  float sc = kv[((row >> 6) * NHEAD + (col >> 7)) * NCH + (row & 63)];
  uint2 u;
  u.x = (unsigned)f2bf(s.x * sc) | ((unsigned)f2bf(s.y * sc) << 16);
  u.y = (unsigned)f2bf(s.z * sc) | ((unsigned)f2bf(s.w * sc) << 16);
  *(uint2*)(t + base) = u;
}

// ===========================================================================
// Tier C fallback (round-1, proven): fp32-staged MFMA GEMM with fused cvt
// ===========================================================================
template<int MODE, bool ABF16, int BM, int BN>
__global__ __launch_bounds__(256) void gemm_bt(
    const void* __restrict__ Ap, const float* __restrict__ B,
    void* __restrict__ C, const float* __restrict__ bias,
    const float* __restrict__ posp, const float* __restrict__ ksc,
    int M, int N, int K)
{
  constexpr int BK = 32;
  constexpr int LDR = BK + 8;
  __shared__ __align__(16) unsigned short As[BM][LDR];
  __shared__ __align__(16) unsigned short Bs[BN][LDR];

  const int tid = threadIdx.x;
  const int m0 = blockIdx.y * BM;
  const int n0 = blockIdx.x * BN;
  constexpr int EA = BM * BK / 256;
  constexpr int EB = BN * BK / 256;
  constexpr int MI = BM / 32;
  constexpr int NI = BN / 32;
  const int lane = tid & 63, wave = tid >> 6;
  const int wr = (wave >> 1) * (BM / 2);
  const int wc = (wave & 1) * (BN / 2);
  const int q = lane >> 4, rl = lane & 15;

  f32x4 acc[MI][NI] = {};

  for (int k0 = 0; k0 < K; k0 += BK) {
    {
      constexpr int CPR = BK / EA;
      int row = tid / CPR;
      int cs  = (tid % CPR) * EA;
      if (ABF16) {
        const unsigned short* a = (const unsigned short*)Ap + (size_t)(m0 + row) * K + k0 + cs;
        #pragma unroll
        for (int v = 0; v < EA / 8; ++v)
          *(uint4*)&As[row][cs + v * 8] = *(const uint4*)(a + v * 8);
      } else {
        const float* a = (const float*)Ap + (size_t)(m0 + row) * K + k0 + cs;
        #pragma unroll
        for (int v = 0; v < EA / 8; ++v) {
          float4 f0 = *(const float4*)(a + v * 8);
          float4 f1 = *(const float4*)(a + v * 8 + 4);
          uint4 u;
          u.x = (unsigned)f2bf(f0.x) | ((unsigned)f2bf(f0.y) << 16);
          u.y = (unsigned)f2bf(f0.z) | ((unsigned)f2bf(f0.w) << 16);
          u.z = (unsigned)f2bf(f1.x) | ((unsigned)f2bf(f1.y) << 16);
          u.w = (unsigned)f2bf(f1.z) | ((unsigned)f2bf(f1.w) << 16);
          *(uint4*)&As[row][cs + v * 8] = u;
        }
      }
    }
    {
      constexpr int CPR = BK / EB;
      int row = tid / CPR;
      int cs  = (tid % CPR) * EB;
      const float* b = B + (size_t)(n0 + row) * K + k0 + cs;
      #pragma unroll
      for (int v = 0; v < EB / 8; ++v) {
        float4 f0 = *(const float4*)(b + v * 8);
        float4 f1 = *(const float4*)(b + v * 8 + 4);
        uint4 u;
        u.x = (unsigned)f2bf(f0.x) | ((unsigned)f2bf(f0.y) << 16);
        u.y = (unsigned)f2bf(f0.z) | ((unsigned)f2bf(f0.w) << 16);
        u.z = (unsigned)f2bf(f1.x) | ((unsigned)f2bf(f1.y) << 16);
        u.w = (unsigned)f2bf(f1.z) | ((unsigned)f2bf(f1.w) << 16);
        *(uint4*)&Bs[row][cs + v * 8] = u;
      }
    }
    __syncthreads();

    short8 af[MI], bf[NI];
    #pragma unroll
    for (int i = 0; i < MI; ++i)
      af[i] = *(const short8*)&As[wr + i * 16 + rl][q * 8];
    #pragma unroll
    for (int j = 0; j < NI; ++j)
      bf[j] = *(const short8*)&Bs[wc + j * 16 + rl][q * 8];
    #pragma unroll
    for (int i = 0; i < MI; ++i)
      #pragma unroll
      for (int j = 0; j < NI; ++j)
        acc[i][j] = __builtin_amdgcn_mfma_f32_16x16x32_bf16(af[i], bf[j], acc[i][j], 0, 0, 0);

    __syncthreads();
  }

  #pragma unroll
  for (int i = 0; i < MI; ++i) {
    #pragma unroll
    for (int j = 0; j < NI; ++j) {
      #pragma unroll
      for (int r = 0; r < 4; ++r) {
        int row = m0 + wr + i * 16 + q * 4 + r;
        int col = n0 + wc + j * 16 + rl;
        float v = acc[i][j][r];
        if (MODE == 0) {
          v += bias[col] + posp[(size_t)(row & 63) * DIMD + col];
          ((unsigned short*)C)[(size_t)row * N + col] = f2bf(v);
        } else if (MODE == 1) {
          v *= ksc[((row >> 6) * NHEAD + (col >> 7)) * NCH + (row & 63)];
          ((unsigned short*)C)[(size_t)row * N + col] = f2bf(v);
        } else {
          ((float*)C)[(size_t)row * N + col] = v + bias[col];
        }
      }
    }
  }
}

// ---- legacy small kernels used by tier C ----
__global__ void wqm_kernel(const float* __restrict__ Wq, float* __restrict__ wqm) {
  int h = blockIdx.x;
  for (int d = threadIdx.x; d < DIMD; d += 256) {
    float s = 0.f;
    const float* p = Wq + (size_t)h * DHEAD * DIMD + d;
    #pragma unroll 4
    for (int e = 0; e < DHEAD; ++e) s += p[(size_t)e * DIMD];
    wqm[h * DIMD + d] = s * (1.0f / DHEAD);
  }
}
__global__ void qk_kernel(const unsigned short* __restrict__ xe,
                          const float* __restrict__ wqm,
                          const float* __restrict__ Wk,
                          float* __restrict__ kout) {
  int b = blockIdx.x;
  __shared__ float qs[NHEAD][NCH];
  for (int t = threadIdx.x; t < NHEAD * NCH; t += 256) {
    int h = t >> 6, c = t & 63;
    const unsigned short* xr = xe + (size_t)(b * NCH + c) * DIMD;
    const float* wr = wqm + h * DIMD;
    float s = 0.f;
    #pragma unroll 8
    for (int d = 0; d < DIMD; ++d) s += bf2f(xr[d]) * wr[d];
    qs[h][c] = s;
  }
  __syncthreads();
  for (int t = threadIdx.x; t < NHEAD * NCH; t += 256) {
    int h = t >> 6, f = t & 63;
    float s = 0.f;
    #pragma unroll
    for (int c = 0; c < NCH; ++c) s += qs[h][c] * Wk[f * NCH + c];
    kout[b * (NHEAD * NCH) + h * NCH + f] = 1.f / (1.f + expf(-s));
  }
}

extern "C" void kernel_launch(void* const* d_in, const int* in_sizes, int n_in,
                              void* d_out, int out_size, void* d_ws, size_t ws_size,
                              hipStream_t stream) {
  const float* x   = (const float*)d_in[0];   // [1024][16384]
  const float* We  = (const float*)d_in[1];   // [1024][16384]
  const float* be  = (const float*)d_in[2];   // [1024]
  const float* pos = (const float*)d_in[3];   // [64][1024]
  const float* Wq  = (const float*)d_in[4];   // [1024][1024]
  const float* Wk  = (const float*)d_in[5];   // [64][64]
  const float* Wv  = (const float*)d_in[6];   // [1024][1024]
  const float* Wo  = (const float*)d_in[7];   // [16384][1024]
  const float* bo  = (const float*)d_in[8];   // [16384]
  float* out = (float*)d_out;                 // [1024][16384] fp32

  const size_t MB = 1u << 20;
  const size_t WS16 = 102 * MB + 64 * 1024;   // tier A
  const size_t WS8  = 70 * MB + 64 * 1024;    // tier B

  if (ws_size >= WS16) {
    char* ws = (char*)d_ws;
    unsigned short* We_bf = (unsigned short*)(ws + 0);           // 32 MB
    unsigned short* Wo_bf = (unsigned short*)(ws + 32 * MB);     // 32 MB
    unsigned short* x_bf  = (unsigned short*)(ws + 64 * MB);     // 32 MB
    unsigned short* Wv_bf = (unsigned short*)(ws + 96 * MB);     // 2 MB
    unsigned short* xe    = (unsigned short*)(ws + 98 * MB);     // 2 MB
    unsigned short* t     = (unsigned short*)(ws + 100 * MB);    // 2 MB
    float* wqm = (float*)(ws + 102 * MB);                        // 32 KB
    float* kv  = (float*)(ws + 102 * MB + 32 * 1024);            // 32 KB

    float* part1 = (float*)d_out;   // [16][1024][1024] = 64 MB (all of d_out)
    float* part2 = (float*)d_out;   // [8][1024][1024]  = 32 MB (part1 dead)

    cvt_bf16_kernel<<<dim3(8192), 256, 0, stream>>>(x,  x_bf,  16777216 / 8);
    cvt_bf16_kernel<<<dim3(8192), 256, 0, stream>>>(We, We_bf, 16777216 / 8);
    cvt_bf16_kernel<<<dim3(512),  256, 0, stream>>>(Wv, Wv_bf, 1048576 / 8);
    cvt_bf16_kernel<<<dim3(8192), 256, 0, stream>>>(Wo, Wo_bf, 16777216 / 8);
    wqm2_kernel<<<dim3(64), 256, 0, stream>>>(Wq, wqm);

    // GEMM1: x @ We^T, splitK=16, XCD-pinned K-slices
    gemm_bf16<3, 1><<<dim3(1024), 256, 0, stream>>>(
        x_bf, We_bf, part1, nullptr, 1024, 1024, 16384, 1024);
    reduce1_kernel<16><<<dim3(1024), 256, 0, stream>>>(part1, be, pos, xe);

    qk2_kernel<<<dim3(16, 8), 256, 0, stream>>>(xe, wqm, Wk, kv);

    // GEMM-v: xe @ Wv^T, splitK=8
    gemm_bf16<3, 0><<<dim3(512), 256, 0, stream>>>(
        xe, Wv_bf, part2, nullptr, 1024, 1024, 1024, 128);
    reduce2_kernel<8><<<dim3(1024), 256, 0, stream>>>(part2, kv, t);

    // final: t @ Wo^T + bo -> out, XCD-pinned Wo column chunks
    gemm_bf16<2, 2><<<dim3(1024), 256, 0, stream>>>(
        t, Wo_bf, out, bo, 1024, 16384, 1024, 1024);
  } else if (ws_size >= WS8) {
    char* ws = (char*)d_ws;
    unsigned short* We_bf = (unsigned short*)(ws + 0);
    unsigned short* Wo_bf = (unsigned short*)(ws + 32 * MB);
    unsigned short* Wv_bf = (unsigned short*)(ws + 64 * MB);
    unsigned short* xe    = (unsigned short*)(ws + 66 * MB);
    unsigned short* t     = (unsigned short*)(ws + 68 * MB);
    float* wqm = (float*)(ws + 70 * MB);
    float* kv  = (float*)(ws + 70 * MB + 32 * 1024);

    char* ob = (char*)d_out;
    unsigned short* x_bf  = (unsigned short*)(ob + 0);
    float* part1 = (float*)(ob + 32 * MB);   // [8][1024][1024] 32 MB
    float* part2 = (float*)(ob + 0);         // [8][1024][1024] 32 MB (x_bf dead)

    cvt_bf16_kernel<<<dim3(8192), 256, 0, stream>>>(x,  x_bf,  16777216 / 8);
    cvt_bf16_kernel<<<dim3(8192), 256, 0, stream>>>(We, We_bf, 16777216 / 8);
    cvt_bf16_kernel<<<dim3(512),  256, 0, stream>>>(Wv, Wv_bf, 1048576 / 8);
    cvt_bf16_kernel<<<dim3(8192), 256, 0, stream>>>(Wo, Wo_bf, 16777216 / 8);
    wqm2_kernel<<<dim3(64), 256, 0, stream>>>(Wq, wqm);

    gemm_bf16<3, 0><<<dim3(512), 256, 0, stream>>>(
        x_bf, We_bf, part1, nullptr, 1024, 1024, 16384, 2048);
    reduce1_kernel<8><<<dim3(1024), 256, 0, stream>>>(part1, be, pos, xe);

    qk2_kernel<<<dim3(16, 8), 256, 0, stream>>>(xe, wqm, Wk, kv);

    gemm_bf16<3, 0><<<dim3(512), 256, 0, stream>>>(
        xe, Wv_bf, part2, nullptr, 1024, 1024, 1024, 128);
    reduce2_kernel<8><<<dim3(1024), 256, 0, stream>>>(part2, kv, t);

    gemm_bf16<2, 2><<<dim3(1024), 256, 0, stream>>>(
        t, Wo_bf, out, bo, 1024, 16384, 1024, 1024);
  } else {
    char* ws = (char*)d_ws;
    unsigned short* xe = (unsigned short*)ws;
    unsigned short* t  = (unsigned short*)(ws + (2u << 20));
    float* wqm = (float*)(ws + (4u << 20));
    float* kv  = (float*)(ws + (4u << 20) + (32u << 10));

    wqm_kernel<<<dim3(NHEAD), 256, 0, stream>>>(Wq, wqm);
    gemm_bt<0, false, 64, 64><<<dim3(16, 16), 256, 0, stream>>>(
        x, We, xe, be, pos, nullptr, 1024, 1024, 16384);
    qk_kernel<<<dim3(16), 256, 0, stream>>>(xe, wqm, Wk, kv);
    gemm_bt<1, true, 64, 64><<<dim3(16, 16), 256, 0, stream>>>(
        xe, Wv, t, nullptr, nullptr, kv, 1024, 1024, 1024);
    gemm_bt<2, true, 128, 128><<<dim3(128, 8), 256, 0, stream>>>(
        t, Wo, out, bo, nullptr, nullptr, 1024, 16384, 1024);
  }
}

// Round 4
// 371.754 us; speedup vs baseline: 2.8601x; 1.0578x over previous
//
#include <hip/hip_runtime.h>
#include <cstdint>
#include <cmath>

// ---------------------------------------------------------------------------
// Vit_Channel_Map: bn=16, C=64, P=16384, DIM=1024, HEADS=8, DH=128
// Tier A (ws >= ~102MB): cvt weights+x -> bf16 (x_bf in ws);
//   GEMM1 splitK=16 (partials = all 64MB of d_out), XCD-pinned K-slices;
//   reduce(+be+pos) -> xe ; wqm/qk ; GEMM-v splitK=8 ; reduce(*k) -> t ;
//   final GEMM XCD-pinned Wo chunks (+bo) -> d_out.
// GEMM core: 128x128 tile, BK=32, global_load_lds width 16, 16x16x32 bf16
// MFMA, 4 waves x 4x4 acc, DOUBLE-BUFFERED one-barrier K-loop:
//   barrier -> issue loads into buf[1-p] -> compute buf[p]
// so the vmcnt(0) drain at each barrier waits loads issued one full compute
// phase earlier (latency overlapped in-wave). R3 evidence: single-buffer loop
// exposed full load latency every iter (MfmaUtil 16%, HBM 20%, L2 fine).
// ---------------------------------------------------------------------------

typedef __attribute__((ext_vector_type(8))) short short8;
typedef __attribute__((ext_vector_type(4))) float f32x4;

#define DIMD 1024
#define NCH  64
#define NHEAD 8
#define DHEAD 128

typedef __attribute__((address_space(1))) unsigned int gu32;
typedef __attribute__((address_space(3))) unsigned int lu32;

__device__ __forceinline__ void gload_lds16(const void* g, void* l) {
  __builtin_amdgcn_global_load_lds((gu32*)g, (lu32*)l, 16, 0, 0);
}

__device__ __forceinline__ unsigned short f2bf(float f) {
  union { float f; unsigned u; } a; a.f = f;
  unsigned u = a.u;
  unsigned r = (u + 0x7fffu + ((u >> 16) & 1u)) >> 16;
  return (unsigned short)r;
}
__device__ __forceinline__ float bf2f(unsigned short h) {
  union { unsigned u; float f; } a; a.u = ((unsigned)h) << 16; return a.f;
}

// ---- elementwise fp32 -> bf16, 8 elems/thread ----
__global__ __launch_bounds__(256) void cvt_bf16_kernel(
    const float* __restrict__ in, unsigned short* __restrict__ out, int n8) {
  int i = blockIdx.x * 256 + threadIdx.x;
  if (i >= n8) return;
  const float4* p = (const float4*)in + (size_t)i * 2;
  float4 f0 = p[0], f1 = p[1];
  uint4 u;
  u.x = (unsigned)f2bf(f0.x) | ((unsigned)f2bf(f0.y) << 16);
  u.y = (unsigned)f2bf(f0.z) | ((unsigned)f2bf(f0.w) << 16);
  u.z = (unsigned)f2bf(f1.x) | ((unsigned)f2bf(f1.y) << 16);
  u.w = (unsigned)f2bf(f1.z) | ((unsigned)f2bf(f1.w) << 16);
  ((uint4*)out)[i] = u;
}

// ---- wqm[h][d] = mean_e Wq[h*128+e][d] ; 64 blocks ----
__global__ __launch_bounds__(256) void wqm2_kernel(
    const float* __restrict__ Wq, float* __restrict__ wqm) {
  int h = blockIdx.x >> 3, dbase = (blockIdx.x & 7) * 128;
  int d = threadIdx.x & 127, eh = threadIdx.x >> 7;
  const float* p = Wq + ((size_t)(h * DHEAD + eh * 64)) * DIMD + dbase + d;
  float s = 0.f;
  #pragma unroll 8
  for (int e = 0; e < 64; ++e) s += p[(size_t)e * DIMD];
  __shared__ float red[2][128];
  red[eh][d] = s;
  __syncthreads();
  if (eh == 0)
    wqm[h * DIMD + dbase + d] = (red[0][d] + red[1][d]) * (1.0f / DHEAD);
}

// ---- q = xe @ wqm^T ; k = sigmoid(q @ Wk^T). Grid (16 batch, 8 head) ----
__global__ __launch_bounds__(256) void qk2_kernel(
    const unsigned short* __restrict__ xe, const float* __restrict__ wqm,
    const float* __restrict__ Wk, float* __restrict__ kout) {
  int b = blockIdx.x, h = blockIdx.y;
  int c = threadIdx.x & 63, dq = threadIdx.x >> 6;
  __shared__ float red[64][4];
  __shared__ float qs[64];
  const uint4* xr = (const uint4*)(xe + ((size_t)(b * NCH + c)) * DIMD + dq * 256);
  const float* wr = wqm + h * DIMD + dq * 256;
  float s = 0.f;
  #pragma unroll 4
  for (int i = 0; i < 32; ++i) {
    uint4 v = xr[i];
    s += bf2f((unsigned short)(v.x & 0xffff)) * wr[i * 8 + 0];
    s += bf2f((unsigned short)(v.x >> 16))    * wr[i * 8 + 1];
    s += bf2f((unsigned short)(v.y & 0xffff)) * wr[i * 8 + 2];
    s += bf2f((unsigned short)(v.y >> 16))    * wr[i * 8 + 3];
    s += bf2f((unsigned short)(v.z & 0xffff)) * wr[i * 8 + 4];
    s += bf2f((unsigned short)(v.z >> 16))    * wr[i * 8 + 5];
    s += bf2f((unsigned short)(v.w & 0xffff)) * wr[i * 8 + 6];
    s += bf2f((unsigned short)(v.w >> 16))    * wr[i * 8 + 7];
  }
  red[c][dq] = s;
  __syncthreads();
  if (dq == 0) qs[c] = red[c][0] + red[c][1] + red[c][2] + red[c][3];
  __syncthreads();
  int f = c;
  float s2 = 0.f;
  #pragma unroll
  for (int i = 0; i < 16; ++i) {
    int cc = dq * 16 + i;
    s2 += qs[cc] * Wk[f * NCH + cc];
  }
  red[f][dq] = s2;
  __syncthreads();
  if (dq == 0) {
    float q = red[f][0] + red[f][1] + red[f][2] + red[f][3];
    kout[(b * NHEAD + h) * NCH + f] = 1.f / (1.f + expf(-q));
  }
}

// ---- double-buffered bf16 GEMM: C = A @ B^T. A:[M][K] bf16, B:[N][K] bf16 ----
// MODE 3: fp32 partial store to C[z][M][N] (split-K) ; MODE 2: C_f32 = acc + bias
// LAYOUT (1D grid, XCD = bid&7 by round-robin dispatch):
//  0: splitK=8  : z=bid&7                ; r=bid>>3: n0=(r&7), m0=(r>>3)
//  1: splitK=16 : z=(bid&7)|((bid>>3&1)<<3); r=bid>>4: n0=(r&7), m0=(r>>3)
//  2: no split  : nblk=(bid&7)+8*(bid>>6); m0=(bid>>3)&7
template<int MODE, int LAYOUT>
__global__ __launch_bounds__(256) void gemm_db(
    const unsigned short* __restrict__ A, const unsigned short* __restrict__ B,
    float* __restrict__ C, const float* __restrict__ bias,
    int M, int N, int K, int Ksub)
{
  __shared__ __align__(16) unsigned short As[2][128][32];
  __shared__ __align__(16) unsigned short Bs[2][128][32];

  const int bid = blockIdx.x;
  int m0, n0, kz;
  if (LAYOUT == 0) {
    kz = bid & 7; int r = bid >> 3; n0 = (r & 7) * 128; m0 = (r >> 3) * 128;
  } else if (LAYOUT == 1) {
    kz = (bid & 7) | (((bid >> 3) & 1) << 3);
    int r = bid >> 4; n0 = (r & 7) * 128; m0 = (r >> 3) * 128;
  } else {
    int nlo = bid & 7, nhi = bid >> 6;
    m0 = ((bid >> 3) & 7) * 128; n0 = (nlo + 8 * nhi) * 128; kz = 0;
  }

  const int tid  = threadIdx.x;
  const int lane = tid & 63, wave = tid >> 6;
  const int kbeg = kz * Ksub;
  const int lrow = lane >> 2;
  const int lcol = (lane & 3) * 8;
  const int q = lane >> 4, rl = lane & 15;
  const int wr = (wave >> 1) * 64, wc = (wave & 1) * 64;

  const unsigned short* ga = A + (size_t)(m0 + wave * 32 + lrow) * K + kbeg + lcol;
  const unsigned short* gb = B + (size_t)(n0 + wave * 32 + lrow) * K + kbeg + lcol;

  f32x4 acc[4][4] = {};

  // preload tile 0 into buffer 0
  gload_lds16(ga,                  &As[0][wave * 32][0]);
  gload_lds16(ga + (size_t)16 * K, &As[0][wave * 32 + 16][0]);
  gload_lds16(gb,                  &Bs[0][wave * 32][0]);
  gload_lds16(gb + (size_t)16 * K, &Bs[0][wave * 32 + 16][0]);
  ga += 32; gb += 32;

  int p = 0;
  for (int k0 = 0; k0 < Ksub; k0 += 32) {
    // barrier drains vmcnt(0): buf[p] loads (issued one compute-phase ago)
    // are ready, and all waves are done reading buf[1-p] from last iter.
    __syncthreads();
    if (k0 + 32 < Ksub) {
      gload_lds16(ga,                  &As[p ^ 1][wave * 32][0]);
      gload_lds16(ga + (size_t)16 * K, &As[p ^ 1][wave * 32 + 16][0]);
      gload_lds16(gb,                  &Bs[p ^ 1][wave * 32][0]);
      gload_lds16(gb + (size_t)16 * K, &Bs[p ^ 1][wave * 32 + 16][0]);
      ga += 32; gb += 32;
    }

    short8 af[4], bf[4];
    #pragma unroll
    for (int i = 0; i < 4; ++i)
      af[i] = *(const short8*)&As[p][wr + i * 16 + rl][q * 8];
    #pragma unroll
    for (int j = 0; j < 4; ++j)
      bf[j] = *(const short8*)&Bs[p][wc + j * 16 + rl][q * 8];
    #pragma unroll
    for (int i = 0; i < 4; ++i)
      #pragma unroll
      for (int j = 0; j < 4; ++j)
        acc[i][j] = __builtin_amdgcn_mfma_f32_16x16x32_bf16(af[i], bf[j], acc[i][j], 0, 0, 0);

    p ^= 1;
  }

  const size_t zoff = (MODE == 3) ? (size_t)kz * (size_t)M * (size_t)N : 0;
  #pragma unroll
  for (int i = 0; i < 4; ++i) {
    #pragma unroll
    for (int j = 0; j < 4; ++j) {
      #pragma unroll
      for (int r = 0; r < 4; ++r) {
        int row = m0 + wr + i * 16 + q * 4 + r;
        int col = n0 + wc + j * 16 + rl;
        if (MODE == 3) {
          C[zoff + (size_t)row * N + col] = acc[i][j][r];
        } else {
          C[(size_t)row * N + col] = acc[i][j][r] + bias[col];
        }
      }
    }
  }
}

// ---- reduce NS splitK partials + be + pos -> bf16 xe ----
template<int NS>
__global__ __launch_bounds__(256) void reduce1_kernel(
    const float* __restrict__ part, const float* __restrict__ be,
    const float* __restrict__ pos, unsigned short* __restrict__ xe) {
  int i = blockIdx.x * 256 + threadIdx.x;
  size_t base = (size_t)i * 4;
  int row = i >> 8, col = (i & 255) * 4;
  float4 s = {0.f, 0.f, 0.f, 0.f};
  #pragma unroll
  for (int sk = 0; sk < NS; ++sk) {
    float4 p = *(const float4*)(part + (size_t)sk * (DIMD * DIMD) + base);
    s.x += p.x; s.y += p.y; s.z += p.z; s.w += p.w;
  }
  float4 bv = *(const float4*)(be + col);
  float4 pv = *(const float4*)(pos + (size_t)(row & 63) * DIMD + col);
  uint2 u;
  u.x = (unsigned)f2bf(s.x + bv.x + pv.x) | ((unsigned)f2bf(s.y + bv.y + pv.y) << 16);
  u.y = (unsigned)f2bf(s.z + bv.z + pv.z) | ((unsigned)f2bf(s.w + bv.w + pv.w) << 16);
  *(uint2*)(xe + base) = u;
}

// ---- reduce NS splitK partials * k-scale -> bf16 t ----
template<int NS>
__global__ __launch_bounds__(256) void reduce2_kernel(
    const float* __restrict__ part, const float* __restrict__ kv,
    unsigned short* __restrict__ t) {
  int i = blockIdx.x * 256 + threadIdx.x;
  size_t base = (size_t)i * 4;
  int row = i >> 8, col = (i & 255) * 4;
  float4 s = {0.f, 0.f, 0.f, 0.f};
  #pragma unroll
  for (int sk = 0; sk < NS; ++sk) {
    float4 p = *(const float4*)(part + (size_t)sk * (DIMD * DIMD) + base);
    s.x += p.x; s.y += p.y; s.z += p.z; s.w += p.w;
  }
  float sc = kv[((row >> 6) * NHEAD + (col >> 7)) * NCH + (row & 63)];
  uint2 u;
  u.x = (unsigned)f2bf(s.x * sc) | ((unsigned)f2bf(s.y * sc) << 16);
  u.y = (unsigned)f2bf(s.z * sc) | ((unsigned)f2bf(s.w * sc) << 16);
  *(uint2*)(t + base) = u;
}

// ===========================================================================
// Tier C fallback (round-1, proven): fp32-staged MFMA GEMM with fused cvt
// ===========================================================================
template<int MODE, bool ABF16, int BM, int BN>
__global__ __launch_bounds__(256) void gemm_bt(
    const void* __restrict__ Ap, const float* __restrict__ B,
    void* __restrict__ C, const float* __restrict__ bias,
    const float* __restrict__ posp, const float* __restrict__ ksc,
    int M, int N, int K)
{
  constexpr int BK = 32;
  constexpr int LDR = BK + 8;
  __shared__ __align__(16) unsigned short As[BM][LDR];
  __shared__ __align__(16) unsigned short Bs[BN][LDR];

  const int tid = threadIdx.x;
  const int m0 = blockIdx.y * BM;
  const int n0 = blockIdx.x * BN;
  constexpr int EA = BM * BK / 256;
  constexpr int EB = BN * BK / 256;
  constexpr int MI = BM / 32;
  constexpr int NI = BN / 32;
  const int lane = tid & 63, wave = tid >> 6;
  const int wr = (wave >> 1) * (BM / 2);
  const int wc = (wave & 1) * (BN / 2);
  const int q = lane >> 4, rl = lane & 15;

  f32x4 acc[MI][NI] = {};

  for (int k0 = 0; k0 < K; k0 += BK) {
    {
      constexpr int CPR = BK / EA;
      int row = tid / CPR;
      int cs  = (tid % CPR) * EA;
      if (ABF16) {
        const unsigned short* a = (const unsigned short*)Ap + (size_t)(m0 + row) * K + k0 + cs;
        #pragma unroll
        for (int v = 0; v < EA / 8; ++v)
          *(uint4*)&As[row][cs + v * 8] = *(const uint4*)(a + v * 8);
      } else {
        const float* a = (const float*)Ap + (size_t)(m0 + row) * K + k0 + cs;
        #pragma unroll
        for (int v = 0; v < EA / 8; ++v) {
          float4 f0 = *(const float4*)(a + v * 8);
          float4 f1 = *(const float4*)(a + v * 8 + 4);
          uint4 u;
          u.x = (unsigned)f2bf(f0.x) | ((unsigned)f2bf(f0.y) << 16);
          u.y = (unsigned)f2bf(f0.z) | ((unsigned)f2bf(f0.w) << 16);
          u.z = (unsigned)f2bf(f1.x) | ((unsigned)f2bf(f1.y) << 16);
          u.w = (unsigned)f2bf(f1.z) | ((unsigned)f2bf(f1.w) << 16);
          *(uint4*)&As[row][cs + v * 8] = u;
        }
      }
    }
    {
      constexpr int CPR = BK / EB;
      int row = tid / CPR;
      int cs  = (tid % CPR) * EB;
      const float* b = B + (size_t)(n0 + row) * K + k0 + cs;
      #pragma unroll
      for (int v = 0; v < EB / 8; ++v) {
        float4 f0 = *(const float4*)(b + v * 8);
        float4 f1 = *(const float4*)(b + v * 8 + 4);
        uint4 u;
        u.x = (unsigned)f2bf(f0.x) | ((unsigned)f2bf(f0.y) << 16);
        u.y = (unsigned)f2bf(f0.z) | ((unsigned)f2bf(f0.w) << 16);
        u.z = (unsigned)f2bf(f1.x) | ((unsigned)f2bf(f1.y) << 16);
        u.w = (unsigned)f2bf(f1.z) | ((unsigned)f2bf(f1.w) << 16);
        *(uint4*)&Bs[row][cs + v * 8] = u;
      }
    }
    __syncthreads();

    short8 af[MI], bf[NI];
    #pragma unroll
    for (int i = 0; i < MI; ++i)
      af[i] = *(const short8*)&As[wr + i * 16 + rl][q * 8];
    #pragma unroll
    for (int j = 0; j < NI; ++j)
      bf[j] = *(const short8*)&Bs[wc + j * 16 + rl][q * 8];
    #pragma unroll
    for (int i = 0; i < MI; ++i)
      #pragma unroll
      for (int j = 0; j < NI; ++j)
        acc[i][j] = __builtin_amdgcn_mfma_f32_16x16x32_bf16(af[i], bf[j], acc[i][j], 0, 0, 0);

    __syncthreads();
  }

  #pragma unroll
  for (int i = 0; i < MI; ++i) {
    #pragma unroll
    for (int j = 0; j < NI; ++j) {
      #pragma unroll
      for (int r = 0; r < 4; ++r) {
        int row = m0 + wr + i * 16 + q * 4 + r;
        int col = n0 + wc + j * 16 + rl;
        float v = acc[i][j][r];
        if (MODE == 0) {
          v += bias[col] + posp[(size_t)(row & 63) * DIMD + col];
          ((unsigned short*)C)[(size_t)row * N + col] = f2bf(v);
        } else if (MODE == 1) {
          v *= ksc[((row >> 6) * NHEAD + (col >> 7)) * NCH + (row & 63)];
          ((unsigned short*)C)[(size_t)row * N + col] = f2bf(v);
        } else {
          ((float*)C)[(size_t)row * N + col] = v + bias[col];
        }
      }
    }
  }
}

// ---- legacy small kernels used by tier C ----
__global__ void wqm_kernel(const float* __restrict__ Wq, float* __restrict__ wqm) {
  int h = blockIdx.x;
  for (int d = threadIdx.x; d < DIMD; d += 256) {
    float s = 0.f;
    const float* p = Wq + (size_t)h * DHEAD * DIMD + d;
    #pragma unroll 4
    for (int e = 0; e < DHEAD; ++e) s += p[(size_t)e * DIMD];
    wqm[h * DIMD + d] = s * (1.0f / DHEAD);
  }
}
__global__ void qk_kernel(const unsigned short* __restrict__ xe,
                          const float* __restrict__ wqm,
                          const float* __restrict__ Wk,
                          float* __restrict__ kout) {
  int b = blockIdx.x;
  __shared__ float qs[NHEAD][NCH];
  for (int t = threadIdx.x; t < NHEAD * NCH; t += 256) {
    int h = t >> 6, c = t & 63;
    const unsigned short* xr = xe + (size_t)(b * NCH + c) * DIMD;
    const float* wr = wqm + h * DIMD;
    float s = 0.f;
    #pragma unroll 8
    for (int d = 0; d < DIMD; ++d) s += bf2f(xr[d]) * wr[d];
    qs[h][c] = s;
  }
  __syncthreads();
  for (int t = threadIdx.x; t < NHEAD * NCH; t += 256) {
    int h = t >> 6, f = t & 63;
    float s = 0.f;
    #pragma unroll
    for (int c = 0; c < NCH; ++c) s += qs[h][c] * Wk[f * NCH + c];
    kout[b * (NHEAD * NCH) + h * NCH + f] = 1.f / (1.f + expf(-s));
  }
}

extern "C" void kernel_launch(void* const* d_in, const int* in_sizes, int n_in,
                              void* d_out, int out_size, void* d_ws, size_t ws_size,
                              hipStream_t stream) {
  const float* x   = (const float*)d_in[0];   // [1024][16384]
  const float* We  = (const float*)d_in[1];   // [1024][16384]
  const float* be  = (const float*)d_in[2];   // [1024]
  const float* pos = (const float*)d_in[3];   // [64][1024]
  const float* Wq  = (const float*)d_in[4];   // [1024][1024]
  const float* Wk  = (const float*)d_in[5];   // [64][64]
  const float* Wv  = (const float*)d_in[6];   // [1024][1024]
  const float* Wo  = (const float*)d_in[7];   // [16384][1024]
  const float* bo  = (const float*)d_in[8];   // [16384]
  float* out = (float*)d_out;                 // [1024][16384] fp32

  const size_t MB = 1u << 20;
  const size_t WS16 = 102 * MB + 64 * 1024;   // tier A
  const size_t WS8  = 70 * MB + 64 * 1024;    // tier B

  if (ws_size >= WS16) {
    char* ws = (char*)d_ws;
    unsigned short* We_bf = (unsigned short*)(ws + 0);           // 32 MB
    unsigned short* Wo_bf = (unsigned short*)(ws + 32 * MB);     // 32 MB
    unsigned short* x_bf  = (unsigned short*)(ws + 64 * MB);     // 32 MB
    unsigned short* Wv_bf = (unsigned short*)(ws + 96 * MB);     // 2 MB
    unsigned short* xe    = (unsigned short*)(ws + 98 * MB);     // 2 MB
    unsigned short* t     = (unsigned short*)(ws + 100 * MB);    // 2 MB
    float* wqm = (float*)(ws + 102 * MB);                        // 32 KB
    float* kv  = (float*)(ws + 102 * MB + 32 * 1024);            // 32 KB

    float* part1 = (float*)d_out;   // [16][1024][1024] = 64 MB
    float* part2 = (float*)d_out;   // [8][1024][1024]  = 32 MB

    cvt_bf16_kernel<<<dim3(8192), 256, 0, stream>>>(x,  x_bf,  16777216 / 8);
    cvt_bf16_kernel<<<dim3(8192), 256, 0, stream>>>(We, We_bf, 16777216 / 8);
    cvt_bf16_kernel<<<dim3(512),  256, 0, stream>>>(Wv, Wv_bf, 1048576 / 8);
    cvt_bf16_kernel<<<dim3(8192), 256, 0, stream>>>(Wo, Wo_bf, 16777216 / 8);
    wqm2_kernel<<<dim3(64), 256, 0, stream>>>(Wq, wqm);

    // GEMM1: x @ We^T, splitK=16, XCD-pinned K-slices
    gemm_db<3, 1><<<dim3(1024), 256, 0, stream>>>(
        x_bf, We_bf, part1, nullptr, 1024, 1024, 16384, 1024);
    reduce1_kernel<16><<<dim3(1024), 256, 0, stream>>>(part1, be, pos, xe);

    qk2_kernel<<<dim3(16, 8), 256, 0, stream>>>(xe, wqm, Wk, kv);

    // GEMM-v: xe @ Wv^T, splitK=8
    gemm_db<3, 0><<<dim3(512), 256, 0, stream>>>(
        xe, Wv_bf, part2, nullptr, 1024, 1024, 1024, 128);
    reduce2_kernel<8><<<dim3(1024), 256, 0, stream>>>(part2, kv, t);

    // final: t @ Wo^T + bo -> out, XCD-pinned Wo column chunks
    gemm_db<2, 2><<<dim3(1024), 256, 0, stream>>>(
        t, Wo_bf, out, bo, 1024, 16384, 1024, 1024);
  } else if (ws_size >= WS8) {
    char* ws = (char*)d_ws;
    unsigned short* We_bf = (unsigned short*)(ws + 0);
    unsigned short* Wo_bf = (unsigned short*)(ws + 32 * MB);
    unsigned short* Wv_bf = (unsigned short*)(ws + 64 * MB);
    unsigned short* xe    = (unsigned short*)(ws + 66 * MB);
    unsigned short* t     = (unsigned short*)(ws + 68 * MB);
    float* wqm = (float*)(ws + 70 * MB);
    float* kv  = (float*)(ws + 70 * MB + 32 * 1024);

    char* ob = (char*)d_out;
    unsigned short* x_bf  = (unsigned short*)(ob + 0);
    float* part1 = (float*)(ob + 32 * MB);   // [8][1024][1024] 32 MB
    float* part2 = (float*)(ob + 0);         // [8][1024][1024] 32 MB

    cvt_bf16_kernel<<<dim3(8192), 256, 0, stream>>>(x,  x_bf,  16777216 / 8);
    cvt_bf16_kernel<<<dim3(8192), 256, 0, stream>>>(We, We_bf, 16777216 / 8);
    cvt_bf16_kernel<<<dim3(512),  256, 0, stream>>>(Wv, Wv_bf, 1048576 / 8);
    cvt_bf16_kernel<<<dim3(8192), 256, 0, stream>>>(Wo, Wo_bf, 16777216 / 8);
    wqm2_kernel<<<dim3(64), 256, 0, stream>>>(Wq, wqm);

    gemm_db<3, 0><<<dim3(512), 256, 0, stream>>>(
        x_bf, We_bf, part1, nullptr, 1024, 1024, 16384, 2048);
    reduce1_kernel<8><<<dim3(1024), 256, 0, stream>>>(part1, be, pos, xe);

    qk2_kernel<<<dim3(16, 8), 256, 0, stream>>>(xe, wqm, Wk, kv);

    gemm_db<3, 0><<<dim3(512), 256, 0, stream>>>(
        xe, Wv_bf, part2, nullptr, 1024, 1024, 1024, 128);
    reduce2_kernel<8><<<dim3(1024), 256, 0, stream>>>(part2, kv, t);

    gemm_db<2, 2><<<dim3(1024), 256, 0, stream>>>(
        t, Wo_bf, out, bo, 1024, 16384, 1024, 1024);
  } else {
    char* ws = (char*)d_ws;
    unsigned short* xe = (unsigned short*)ws;
    unsigned short* t  = (unsigned short*)(ws + (2u << 20));
    float* wqm = (float*)(ws + (4u << 20));
    float* kv  = (float*)(ws + (4u << 20) + (32u << 10));

    wqm_kernel<<<dim3(NHEAD), 256, 0, stream>>>(Wq, wqm);
    gemm_bt<0, false, 64, 64><<<dim3(16, 16), 256, 0, stream>>>(
        x, We, xe, be, pos, nullptr, 1024, 1024, 16384);
    qk_kernel<<<dim3(16), 256, 0, stream>>>(xe, wqm, Wk, kv);
    gemm_bt<1, true, 64, 64><<<dim3(16, 16), 256, 0, stream>>>(
        xe, Wv, t, nullptr, nullptr, kv, 1024, 1024, 1024);
    gemm_bt<2, true, 128, 128><<<dim3(128, 8), 256, 0, stream>>>(
        t, Wo, out, bo, nullptr, nullptr, 1024, 16384, 1024);
  }
}